// Round 2
// 605.454 us; speedup vs baseline: 1.0251x; 1.0251x over previous
//
#include <hip/hip_runtime.h>

// 3x3 reflect-padded patch extraction.
// x: [8, 256, 256, 32] f32  ->  out: [8, 256, 256, 288] f32
// out[b,h,w, c*9 + i] = x[b, refl(h + i/3 - 1), refl(w + i%3 - 1), c]
//
// v4b: barrier-free wave-private pipeline (v4 with nontemporal-store type fix:
//      __builtin_nontemporal_store needs a clang ext_vector_type, not HIP's
//      struct float4).
//  - 9 tap loads/thread straight from global (L1/L2-hot, coalesced ~1KB/wave).
//  - register repack into output layout, LDS transpose within the wave's own
//    8-pixel quadrant only (rows 8*wv .. 8*wv+7). Per-wave DS ops execute in
//    order, so compiler-inserted lgkmcnt ordering replaces __syncthreads():
//    no inter-wave rendezvous, each of the 16 waves/CU streams independently.
//  - LDS banking: (addr/16) mod 8 == (cg+m) mod 8 -> every 8 consecutive
//    lanes cover 8 distinct 16B bank groups; both b128 write and read run at
//    full 128 B/clk (verified by hand, no swizzle needed).
//  - coalesced contiguous float4 stores (1KB/wave/inst, full 64B lines),
//    nontemporal: output is write-once, keep it from thrashing L2 so input
//    rows stay resident for the h-1/h/h+1 reuse window.

#define BB 8
#define HH 256
#define WW 256
#define CC 32
#define TAPS 9
#define OUTC (CC * TAPS)    // 288
#define TW 32               // w-tile per block
#define NTW (WW / TW)       // 8 tiles per row

typedef float f32x4 __attribute__((ext_vector_type(4)));  // native vec for nt-store

__device__ __forceinline__ int refl(int i, int n) {
    // np.pad mode='reflect', valid for i in [-1, n]
    return i < 0 ? -i : (i >= n ? 2 * n - 2 - i : i);
}

__global__ __launch_bounds__(256) void patch3x3_v4(
    const float* __restrict__ x, float* __restrict__ out) {
    const int blk = blockIdx.x;
    const int wt = blk % NTW;
    const int h  = (blk / NTW) % HH;
    const int b  = blk / (NTW * HH);
    const int w0 = wt * TW;
    const int t  = threadIdx.x;

    __shared__ float out_lds[TW][OUTC];         // 36864 B

    // ---- tap gather straight from global (wave-uniform row bases) ----
    const float* xb = x + (size_t)b * HH * WW * CC;
    const float* row0 = xb + (size_t)refl(h - 1, HH) * WW * CC;
    const float* row1 = xb + (size_t)h * WW * CC;
    const float* row2 = xb + (size_t)refl(h + 1, HH) * WW * CC;

    const int p  = t >> 3;      // pixel in tile, 0..31 (wave wv owns 8wv..8wv+7)
    const int cg = t & 7;       // channel group of 4, 0..7

    int coff[3];
#pragma unroll
    for (int kj = 0; kj < 3; ++kj)
        coff[kj] = refl(w0 + p + kj - 1, WW) * CC + cg * 4;

    f32x4 q[3][3];
#pragma unroll
    for (int kj = 0; kj < 3; ++kj) {
        q[0][kj] = *(const f32x4*)(row0 + coff[kj]);
        q[1][kj] = *(const f32x4*)(row1 + coff[kj]);
        q[2][kj] = *(const f32x4*)(row2 + coff[kj]);
    }

    // ---- repack (pure register selects) + LDS write in output layout ----
    // local flat f = cl*9 + i, cl in [0,4), i = 3*ki + kj
#pragma unroll
    for (int m = 0; m < 9; ++m) {
        f32x4 v;
#pragma unroll
        for (int k = 0; k < 4; ++k) {
            const int f  = 4 * m + k;   // compile-time
            const int cl = f / 9;
            const int i  = f % 9;
            const int ki = i / 3;
            const int kj = i % 3;
            v[k] = q[ki][kj][cl];
        }
        *(f32x4*)&out_lds[p][cg * 36 + 4 * m] = v;
    }

    // ---- NO __syncthreads(): wave reads back only its own quadrant ----
    // wave wv wrote LDS rows [8wv, 8wv+8); float4 range [576wv, 576wv+576).
    // Per-wave DS ordering + lgkmcnt makes this safe without a barrier.
    const int wv = t >> 6;
    const int l  = t & 63;
    f32x4* outp = (f32x4*)(out + (size_t)((b * HH + h) * WW + w0) * OUTC);
    const f32x4* src4 = (const f32x4*)&out_lds[0][0];
#pragma unroll
    for (int it = 0; it < TAPS; ++it) {         // 9 iters, 1KB/wave each
        const int idx = wv * 576 + 64 * it + l; // contiguous across the wave
        __builtin_nontemporal_store(src4[idx], &outp[idx]);
    }
}

extern "C" void kernel_launch(void* const* d_in, const int* in_sizes, int n_in,
                              void* d_out, int out_size, void* d_ws, size_t ws_size,
                              hipStream_t stream) {
    const float* x = (const float*)d_in[0];
    float* out = (float*)d_out;
    const int nblocks = BB * HH * NTW;   // 16384
    patch3x3_v4<<<nblocks, 256, 0, stream>>>(x, out);
}